// Round 8
// baseline (162.126 us; speedup 1.0000x reference)
//
#include <hip/hip_runtime.h>

// Multi-scale gradient-difference loss as line-parallel reductions.
// R8: collapse 5 graph nodes -> 2 to kill inter-dispatch gaps (~25-35 us).
//  - pass1 stores per-block partials (no init needed); block 0 zeroes the
//    T1 accumulators + completion counter for pass2 (kernel boundary orders).
//  - pass2 computes invC per block from pass1 partials (plain loads across
//    kernel boundary = coherent), then finishes with a last-block pattern:
//    f64 atomic T1 adds -> threadfence -> counter; the last block re-reduces
//    partials + reads T1 via atomic-returning adds (coherent point, avoids
//    the R4 cross-XCD stale-load trap) and writes out[0..2].
// Inner loops keep R6's placement-independent (scale,quarter) round-robin
// deal: ~49 tasks/wave regardless of block->CU placement.

#define NSCALES 67
#define IMG_H 256
#define IMG_W 256
#define NPIX 65536
#define NLINES 2046          // 512 rows (H) + 512 cols (V) + 1022 diagonals (D)
#define LMAX_PAD 320         // 256 positions + 64 zero pad (max tap index 318)

// ws layout (doubles):
//  [24..25] T1[b] (atomic accum, zeroed by pass1 block 0)
//  [26]     completion counter (int, zeroed by pass1 block 0)
//  [32 + id*5 + j] pass1 per-line partials j={S1,S2,posCnt,sumAbsPrd,roiH}
#define T1_OFF 24
#define CNT_OFF 26
#define PART_OFF 32

__device__ __forceinline__ double wave_red(double v) {
#pragma unroll
  for (int o = 32; o > 0; o >>= 1) v += __shfl_down(v, o, 64);
  return v;
}

__device__ __forceinline__ void decode_line(int id, int& b, int& base, int& stride, int& L) {
  if (id < 512) {                      // horizontal row
    b = id >> 8; int y = id & 255;
    base = y * IMG_W; stride = 1; L = IMG_W;
  } else if (id < 1024) {              // vertical column
    int t = id - 512; b = t >> 8;
    base = t & 255; stride = IMG_W; L = IMG_H;
  } else {                             // diagonal c = x - y in [-255,255]
    int t = id - 1024; b = (t >= 511) ? 1 : 0;
    int d = t - b * 511; int c = d - 255;
    int ac = (c < 0) ? -c : c;
    base = (c < 0) ? (-c) * IMG_W : c;
    stride = IMG_W + 1; L = 256 - ac;
  }
}

__device__ __forceinline__ int line_batch(int id) {
  if (id < 512) return id >> 8;
  if (id < 1024) return (id - 512) >> 8;
  return (id - 1024) >= 511 ? 1 : 0;
}

// #scales valid for quarter q (centers [64q, 64q+63]): s = 1+3k <= min(L-1-64q, 199)
__device__ __forceinline__ int scale_count(int L, int q) {
  int rem = L - 1 - (q << 6);
  int kcnt = (rem >= 1) ? ((rem - 1) / 3 + 1) : 0;
  return (kcnt > NSCALES) ? NSCALES : kcnt;
}

// Stage line; returns this tid's ROI value (position tid) for the ROI sum.
__device__ __forceinline__ float stage_line(
    const float* __restrict__ Pred, const float* __restrict__ GT,
    const float* __restrict__ ROI, int b, int base, int stride, int L,
    int tid, float4* bufA, float4* bufB) {
  const float* P = Pred + b * (3 * NPIX);
  const float* G = GT + b * (3 * NPIX);
  const float* R = ROI + b * NPIX;
  float r = 0.f, p0 = 0.f, p1 = 0.f, p2 = 0.f, g0 = 0.f, g1 = 0.f, g2 = 0.f;
  if (tid < L) {
    int a = base + tid * stride;
    r = R[a];
    p0 = P[a]; p1 = P[a + NPIX]; p2 = P[a + 2 * NPIX];
    g0 = G[a]; g1 = G[a + NPIX]; g2 = G[a + 2 * NPIX];
  }
  bufA[tid] = make_float4(r, p0, p1, p2);
  bufB[tid] = make_float4(g0, g1, g2, 0.f);
  if (tid < LMAX_PAD - 256) {
    bufA[256 + tid] = make_float4(0.f, 0.f, 0.f, 0.f);
    bufB[256 + tid] = make_float4(0.f, 0.f, 0.f, 0.f);
  }
  __syncthreads();
  return r;
}

extern "C" __global__ void __launch_bounds__(256, 8) pass1_kernel(
    const float* __restrict__ Pred, const float* __restrict__ GT,
    const float* __restrict__ ROI, double* __restrict__ ws) {
  __shared__ float4 bufA[LMAX_PAD];    // {r, p0, p1, p2}
  __shared__ float4 bufB[LMAX_PAD];    // {g0, g1, g2, 0}
  __shared__ double red[4][5];
  const int id = blockIdx.x;
  const int tid = threadIdx.x;
  const int wid = tid >> 6, lane = tid & 63;

  if (id == 0 && tid == 0) {           // init for pass2 (kernel boundary orders)
    ws[T1_OFF + 0] = 0.0;
    ws[T1_OFF + 1] = 0.0;
    ((int*)&ws[CNT_OFF])[0] = 0;
  }

  int b, base, stride, L;
  decode_line(id, b, base, stride, L);
  float stg_r = stage_line(Pred, GT, ROI, b, base, stride, L, tid, bufA, bufB);

  float f1 = 0.f, f2 = 0.f, fp = 0.f;
  int pci = 0;
  int P = 0;                            // task prefix
  for (int q = 0; q < 4; ++q) {
    const int Kq = scale_count(L, q);
    int k = (wid - P) & 3;              // first task of run q owned by this wave
    if (k < Kq) {
      const int c = (q << 6) + lane;
      const float4 cA = bufA[c];
      const float4 cB = bufB[c];
      const float cr = cA.x, cp0 = cA.y, cp1 = cA.z, cp2 = cA.w;
      const float cg0 = cB.x, cg1 = cB.y, cg2 = cB.z;
      const float4* tA = &bufA[c + 1 + 3 * k];
      const float4* tB = &bufB[c + 1 + 3 * k];
#pragma unroll 2
      for (; k < Kq; k += 4) {
        float4 t0 = tA[0];
        float4 t1 = tB[0];
        tA += 12; tB += 12;             // s += 12
        float rr = cr * t0.x;
#define L1BODY(cp, cg, tp, tg)                                   \
        {                                                        \
          float dP = rr * (cp - tp);                             \
          float dG = rr * (cg - tg);                             \
          float qq = dP * __builtin_amdgcn_rcpf(dG + 1e-5f);     \
          float aG = fabsf(dG);                                  \
          f1 += fmaxf(aG * qq, 0.f);                             \
          if (qq > 0.f) f2 += aG;                                \
          if (dG > 0.f) pci++;                                   \
          fp += fabsf(dP);                                       \
        }
        L1BODY(cp0, cg0, t0.y, t1.x)
        L1BODY(cp1, cg1, t0.z, t1.y)
        L1BODY(cp2, cg2, t0.w, t1.z)
#undef L1BODY
      }
    }
    P += Kq;
  }

  double w0 = wave_red((double)f1);
  double w1 = wave_red((double)f2);
  double w2 = wave_red((double)pci);
  double w3 = wave_red((double)fp);
  double w4 = wave_red((double)((id < 512) ? stg_r : 0.f));  // ROI: H rows only
  if (lane == 0) {
    red[wid][0] = w0; red[wid][1] = w1; red[wid][2] = w2;
    red[wid][3] = w3; red[wid][4] = w4;
  }
  __syncthreads();
  if (tid < 5)                          // plain stores: no init needed
    ws[PART_OFF + id * 5 + tid] =
        red[0][tid] + red[1][tid] + red[2][tid] + red[3][tid];
}

extern "C" __global__ void __launch_bounds__(256, 8) pass2_kernel(
    const float* __restrict__ Pred, const float* __restrict__ GT,
    const float* __restrict__ ROI, double* __restrict__ ws,
    float* __restrict__ out) {
  __shared__ float4 bufA[LMAX_PAD];
  __shared__ float4 bufB[LMAX_PAD];
  __shared__ double red[4];
  __shared__ float s_invC;
  __shared__ int s_isLast;
  const int id = blockIdx.x;
  const int tid = threadIdx.x;
  const int wid = tid >> 6, lane = tid & 63;

  int b, base, stride, L;
  decode_line(id, b, base, stride, L);
  stage_line(Pred, GT, ROI, b, base, stride, L, tid, bufA, bufB);

  if (wid == 0) {                       // invC from pass1 partials (coherent
    double s1 = 0.0, s2 = 0.0;          // across the kernel boundary)
    for (int p = lane; p < NLINES; p += 64) {
      bool mine = (line_batch(p) == b);
      s1 += mine ? ws[PART_OFF + p * 5 + 0] : 0.0;
      s2 += mine ? ws[PART_OFF + p * 5 + 1] : 0.0;
    }
    s1 = wave_red(s1); s2 = wave_red(s2);
    if (lane == 0) {
      float cc = (float)(s1 / (s2 + 1e-4));
      s_invC = (cc > 1e-4f) ? (float)(1.0 / (double)cc) : 1.0f;
    }
  }
  __syncthreads();
  const float invC = s_invC;

  float f = 0.f;
  int P = 0;
  for (int q = 0; q < 4; ++q) {
    const int Kq = scale_count(L, q);
    int k = (wid - P) & 3;
    if (k < Kq) {
      const int c = (q << 6) + lane;
      const float4 cA = bufA[c];
      const float4 cB = bufB[c];
      const float cr = cA.x, cp0 = cA.y, cp1 = cA.z, cp2 = cA.w;
      const float cg0 = cB.x, cg1 = cB.y, cg2 = cB.z;
      const float4* tA = &bufA[c + 1 + 3 * k];
      const float4* tB = &bufB[c + 1 + 3 * k];
#pragma unroll 2
      for (; k < Kq; k += 4) {
        float4 t0 = tA[0];
        float4 t1 = tB[0];
        tA += 12; tB += 12;
        float rr = cr * t0.x;
        // |difGT - difPrd/c| = rr * |(g-gt) - (p-pt)*invC|   (rr in {0,1})
        f += rr * fabsf((cg0 - t1.x) - (cp0 - t0.y) * invC);
        f += rr * fabsf((cg1 - t1.y) - (cp1 - t0.z) * invC);
        f += rr * fabsf((cg2 - t1.z) - (cp2 - t0.w) * invC);
      }
    }
    P += Kq;
  }
  double t = wave_red((double)f);
  if (lane == 0) red[wid] = t;
  __syncthreads();
  if (tid == 0) {
    unsafeAtomicAdd(&ws[T1_OFF + b], red[0] + red[1] + red[2] + red[3]);
    __threadfence();                    // T1 add visible before counter bump
    int old = atomicAdd((int*)&ws[CNT_OFF], 1);
    s_isLast = (old == NLINES - 1);
  }
  __syncthreads();

  if (!s_isLast) return;

  // ---- last block: final reduction + scalar epilogue ----
  if (wid == 0) {
    double a0[5] = {0, 0, 0, 0, 0}, a1[5] = {0, 0, 0, 0, 0};
    for (int p = lane; p < NLINES; p += 64) {
      bool b1 = (line_batch(p) == 1);
#pragma unroll
      for (int j = 0; j < 5; ++j) {
        double v = ws[PART_OFF + p * 5 + j];
        a0[j] += b1 ? 0.0 : v;
        a1[j] += b1 ? v : 0.0;
      }
    }
#pragma unroll
    for (int j = 0; j < 5; ++j) { a0[j] = wave_red(a0[j]); a1[j] = wave_red(a1[j]); }
    if (lane == 0) {
      __threadfence();
      double T1v[2];
      T1v[0] = unsafeAtomicAdd(&ws[T1_OFF + 0], 0.0);   // coherent read-back
      T1v[1] = unsafeAtomicAdd(&ws[T1_OFF + 1], 0.0);
      double S1[2] = {a0[0], a1[0]}, S2[2] = {a0[1], a1[1]};
      double PC[2] = {a0[2], a1[2]}, SP[2] = {a0[3], a1[3]};
      double RS[2] = {a0[4], a1[4]};
      double loss = 0.0;
      for (int bb = 0; bb < 2; ++bb) {
        float cc = (float)(S1[bb] / (S2[bb] + 1e-4));
        out[1 + bb] = cc;               // NormConst
        double term1 = (cc > 1e-4f) ? T1v[bb] / (603.0 * 65536.0) : 0.0;
        float meanPrd = (float)(SP[bb] / PC[bb]);
        bool big = RS[bb] > 200.0;
        float t2 = (big && meanPrd > 30.f && cc > 10.f) ? (meanPrd - 30.f) : 0.f;
        float fact = 0.1f / (cc + 0.001f);
        float t3 = (big && meanPrd < 2.f && cc < 0.1f) ? (0.2f - meanPrd) * fact : 0.f;
        loss += term1 + (double)(t2 + t3);
      }
      out[0] = (float)loss;
    }
  }
}

extern "C" void kernel_launch(void* const* d_in, const int* in_sizes, int n_in,
                              void* d_out, int out_size, void* d_ws, size_t ws_size,
                              hipStream_t stream) {
  (void)in_sizes; (void)n_in; (void)out_size; (void)ws_size;
  const float* Pred = (const float*)d_in[0];
  const float* GT = (const float*)d_in[1];
  const float* ROI = (const float*)d_in[2];
  float* out = (float*)d_out;
  double* ws = (double*)d_ws;

  hipLaunchKernelGGL(pass1_kernel, dim3(NLINES), dim3(256), 0, stream,
                     Pred, GT, ROI, ws);
  hipLaunchKernelGGL(pass2_kernel, dim3(NLINES), dim3(256), 0, stream,
                     Pred, GT, ROI, ws, out);
}

// Round 11
// 152.412 us; speedup vs baseline: 1.0637x; 1.0637x over previous
//
#include <hip/hip_runtime.h>

// Multi-scale gradient-difference loss as line-parallel reductions.
// R11: NO cooperative launch. R4/R9/R10 failed with the bit-identical error
// 0.8515625 = |loss_ref - 0| across three readback mechanisms -> the coop
// kernel never ran (launch error ignored); out stayed memset-zero. R8's
// plain-launch device-atomic + counter + last-block pattern PASSED, so:
//   memset(128B) -> pass1 (atomic sums, R7-proven) -> pass2 (invC via 2
//   plain f64 loads across kernel boundary [R5/R7-proven], phase B, then
//   R8-proven last-block epilogue: T1 atomic add -> threadfence -> counter;
//   last block reads T1 via atomic-add readback, writes out[0..2]).
// Inner loops keep the placement-independent (scale,quarter) round-robin
// task deal (~49 tasks/wave regardless of block->CU placement).

#define NSCALES 67
#define IMG_H 256
#define IMG_W 256
#define NPIX 65536
#define NLINES 2046          // 512 rows (H) + 512 cols (V) + 1022 diagonals (D)
#define LMAX_PAD 320         // 256 positions + 64 zero pad (max tap index 318)

// ws layout (doubles), memset to 0 each launch:
//  [0..4]  b0 {S1, S2, posCnt, sumAbsPrd, roiSum}
//  [5..9]  b1 same
//  [10..11] T1[b]
//  [12]     completion counter (int)
#define T1_OFF 10
#define CNT_OFF 12

__device__ __forceinline__ double wave_red(double v) {
#pragma unroll
  for (int o = 32; o > 0; o >>= 1) v += __shfl_down(v, o, 64);
  return v;
}

__device__ __forceinline__ void decode_line(int id, int& b, int& base, int& stride, int& L) {
  if (id < 512) {                      // horizontal row
    b = id >> 8; int y = id & 255;
    base = y * IMG_W; stride = 1; L = IMG_W;
  } else if (id < 1024) {              // vertical column
    int t = id - 512; b = t >> 8;
    base = t & 255; stride = IMG_W; L = IMG_H;
  } else {                             // diagonal c = x - y in [-255,255]
    int t = id - 1024; b = (t >= 511) ? 1 : 0;
    int d = t - b * 511; int c = d - 255;
    int ac = (c < 0) ? -c : c;
    base = (c < 0) ? (-c) * IMG_W : c;
    stride = IMG_W + 1; L = 256 - ac;
  }
}

// #scales valid for quarter q (centers [64q,64q+63]): s = 1+3k <= min(L-1-64q, 199)
__device__ __forceinline__ int scale_count(int L, int q) {
  int rem = L - 1 - (q << 6);
  int kcnt = (rem >= 1) ? ((rem - 1) / 3 + 1) : 0;
  return (kcnt > NSCALES) ? NSCALES : kcnt;
}

// Stage line into split float4 LDS; returns this tid's ROI value.
__device__ __forceinline__ float stage_line(
    const float* __restrict__ Pred, const float* __restrict__ GT,
    const float* __restrict__ ROI, int b, int base, int stride, int L,
    int tid, float4* bufA, float4* bufB) {
  const float* P = Pred + b * (3 * NPIX);
  const float* G = GT + b * (3 * NPIX);
  const float* R = ROI + b * NPIX;
  float r = 0.f, p0 = 0.f, p1 = 0.f, p2 = 0.f, g0 = 0.f, g1 = 0.f, g2 = 0.f;
  if (tid < L) {
    int a = base + tid * stride;
    r = R[a];
    p0 = P[a]; p1 = P[a + NPIX]; p2 = P[a + 2 * NPIX];
    g0 = G[a]; g1 = G[a + NPIX]; g2 = G[a + 2 * NPIX];
  }
  bufA[tid] = make_float4(r, p0, p1, p2);
  bufB[tid] = make_float4(g0, g1, g2, 0.f);
  if (tid < LMAX_PAD - 256) {
    bufA[256 + tid] = make_float4(0.f, 0.f, 0.f, 0.f);
    bufB[256 + tid] = make_float4(0.f, 0.f, 0.f, 0.f);
  }
  __syncthreads();
  return r;
}

extern "C" __global__ void __launch_bounds__(256, 8) pass1_kernel(
    const float* __restrict__ Pred, const float* __restrict__ GT,
    const float* __restrict__ ROI, double* __restrict__ ws) {
  __shared__ float4 bufA[LMAX_PAD];    // {r, p0, p1, p2}
  __shared__ float4 bufB[LMAX_PAD];    // {g0, g1, g2, 0}
  __shared__ double red[4][5];
  const int id = blockIdx.x;
  const int tid = threadIdx.x;
  const int wid = tid >> 6, lane = tid & 63;

  int b, base, stride, L;
  decode_line(id, b, base, stride, L);
  float stg_r = stage_line(Pred, GT, ROI, b, base, stride, L, tid, bufA, bufB);

  float f1 = 0.f, f2 = 0.f, fp = 0.f;
  int pci = 0;
  int P = 0;                            // task prefix
  for (int q = 0; q < 4; ++q) {
    const int Kq = scale_count(L, q);
    int k = (wid - P) & 3;              // first task of run q owned by this wave
    if (k < Kq) {
      const int c = (q << 6) + lane;
      const float4 cA = bufA[c];
      const float4 cB = bufB[c];
      const float cr = cA.x, cp0 = cA.y, cp1 = cA.z, cp2 = cA.w;
      const float cg0 = cB.x, cg1 = cB.y, cg2 = cB.z;
      const float4* tA = &bufA[c + 1 + 3 * k];
      const float4* tB = &bufB[c + 1 + 3 * k];
#pragma unroll 2
      for (; k < Kq; k += 4) {
        float4 t0 = tA[0];
        float4 t1 = tB[0];
        tA += 12; tB += 12;             // s += 12
        float rr = cr * t0.x;
#define L1BODY(cp, cg, tp, tg)                                   \
        {                                                        \
          float dP = rr * (cp - tp);                             \
          float dG = rr * (cg - tg);                             \
          float qq = dP * __builtin_amdgcn_rcpf(dG + 1e-5f);     \
          float aG = fabsf(dG);                                  \
          f1 += fmaxf(aG * qq, 0.f);                             \
          if (qq > 0.f) f2 += aG;                                \
          if (dG > 0.f) pci++;                                   \
          fp += fabsf(dP);                                       \
        }
        L1BODY(cp0, cg0, t0.y, t1.x)
        L1BODY(cp1, cg1, t0.z, t1.y)
        L1BODY(cp2, cg2, t0.w, t1.z)
#undef L1BODY
      }
    }
    P += Kq;
  }

  double w0 = wave_red((double)f1);
  double w1 = wave_red((double)f2);
  double w2 = wave_red((double)pci);
  double w3 = wave_red((double)fp);
  double w4 = wave_red((double)((id < 512) ? stg_r : 0.f));  // ROI: H rows only
  if (lane == 0) {
    red[wid][0] = w0; red[wid][1] = w1; red[wid][2] = w2;
    red[wid][3] = w3; red[wid][4] = w4;
  }
  __syncthreads();
  if (tid < 5)                          // 5 lanes -> 5 distinct accumulators
    unsafeAtomicAdd(&ws[b * 5 + tid],
                    red[0][tid] + red[1][tid] + red[2][tid] + red[3][tid]);
}

extern "C" __global__ void __launch_bounds__(256, 8) pass2_kernel(
    const float* __restrict__ Pred, const float* __restrict__ GT,
    const float* __restrict__ ROI, double* __restrict__ ws,
    float* __restrict__ out) {
  __shared__ float4 bufA[LMAX_PAD];
  __shared__ float4 bufB[LMAX_PAD];
  __shared__ double red[4];
  __shared__ float s_invC;
  __shared__ int s_isLast;
  const int id = blockIdx.x;
  const int tid = threadIdx.x;
  const int wid = tid >> 6, lane = tid & 63;

  int b, base, stride, L;
  decode_line(id, b, base, stride, L);
  if (tid == 0) {                       // 2 plain f64 loads across the kernel
    double S1 = ws[b * 5 + 0];          // boundary (R5/R7-proven coherent)
    double S2 = ws[b * 5 + 1];
    float cc = (float)(S1 / (S2 + 1e-4));
    s_invC = (cc > 1e-4f) ? (float)(1.0 / (double)cc) : 1.0f;
  }
  stage_line(Pred, GT, ROI, b, base, stride, L, tid, bufA, bufB);

  const float invC = s_invC;
  float f = 0.f;
  int P = 0;
  for (int q = 0; q < 4; ++q) {
    const int Kq = scale_count(L, q);
    int k = (wid - P) & 3;
    if (k < Kq) {
      const int c = (q << 6) + lane;
      const float4 cA = bufA[c];
      const float4 cB = bufB[c];
      const float cr = cA.x, cp0 = cA.y, cp1 = cA.z, cp2 = cA.w;
      const float cg0 = cB.x, cg1 = cB.y, cg2 = cB.z;
      const float4* tA = &bufA[c + 1 + 3 * k];
      const float4* tB = &bufB[c + 1 + 3 * k];
#pragma unroll 2
      for (; k < Kq; k += 4) {
        float4 t0 = tA[0];
        float4 t1 = tB[0];
        tA += 12; tB += 12;
        float rr = cr * t0.x;
        // |difGT - difPrd/c| = rr * |(g-gt) - (p-pt)*invC|   (rr in {0,1})
        f += rr * fabsf((cg0 - t1.x) - (cp0 - t0.y) * invC);
        f += rr * fabsf((cg1 - t1.y) - (cp1 - t0.z) * invC);
        f += rr * fabsf((cg2 - t1.z) - (cp2 - t0.w) * invC);
      }
    }
    P += Kq;
  }
  double t = wave_red((double)f);
  if (lane == 0) red[wid] = t;
  __syncthreads();
  if (tid == 0) {
    unsafeAtomicAdd(&ws[T1_OFF + b], red[0] + red[1] + red[2] + red[3]);
    __threadfence();                    // T1 add visible before counter bump
    int old = atomicAdd((int*)&ws[CNT_OFF], 1);
    s_isLast = (old == NLINES - 1);
  }
  __syncthreads();

  if (s_isLast && tid == 0) {           // R8-proven last-block epilogue
    __threadfence();
    double T1v[2];
    T1v[0] = unsafeAtomicAdd(&ws[T1_OFF + 0], 0.0);   // atomic readback
    T1v[1] = unsafeAtomicAdd(&ws[T1_OFF + 1], 0.0);
    double loss = 0.0;
    for (int bb = 0; bb < 2; ++bb) {
      double S1 = ws[bb * 5 + 0], S2 = ws[bb * 5 + 1];  // pass1-written: plain
      double PC = ws[bb * 5 + 2], SP = ws[bb * 5 + 3];  // loads are coherent
      double RS = ws[bb * 5 + 4];                       // across the boundary
      float cc = (float)(S1 / (S2 + 1e-4));
      out[1 + bb] = cc;                 // NormConst
      double term1 = (cc > 1e-4f) ? T1v[bb] / (603.0 * 65536.0) : 0.0;
      float meanPrd = (float)(SP / PC);
      bool big = RS > 200.0;
      float t2 = (big && meanPrd > 30.f && cc > 10.f) ? (meanPrd - 30.f) : 0.f;
      float fact = 0.1f / (cc + 0.001f);
      float t3 = (big && meanPrd < 2.f && cc < 0.1f) ? (0.2f - meanPrd) * fact : 0.f;
      loss += term1 + (double)(t2 + t3);
    }
    out[0] = (float)loss;
  }
}

extern "C" void kernel_launch(void* const* d_in, const int* in_sizes, int n_in,
                              void* d_out, int out_size, void* d_ws, size_t ws_size,
                              hipStream_t stream) {
  (void)in_sizes; (void)n_in; (void)out_size; (void)ws_size;
  const float* Pred = (const float*)d_in[0];
  const float* GT = (const float*)d_in[1];
  const float* ROI = (const float*)d_in[2];
  float* out = (float*)d_out;
  double* ws = (double*)d_ws;

  hipMemsetAsync(d_ws, 0, 16 * sizeof(double), stream);   // sums+T1+counter
  hipLaunchKernelGGL(pass1_kernel, dim3(NLINES), dim3(256), 0, stream,
                     Pred, GT, ROI, ws);
  hipLaunchKernelGGL(pass2_kernel, dim3(NLINES), dim3(256), 0, stream,
                     Pred, GT, ROI, ws, out);
}

// Round 12
// 152.258 us; speedup vs baseline: 1.0648x; 1.0010x over previous
//
#include <hip/hip_runtime.h>

// Multi-scale gradient-difference loss as line-parallel reductions.
// R12 = R11 minus __threadfence(). R11's pass2 was 65us @ VALUBusy 13.5%:
// the per-block agent-scope fence (buffer_wbl2 + buffer_inv) invalidated
// each XCD's L1/L2 2046 times, destroying staging locality for all
// co-resident blocks (latency-bound; FETCH unchanged because MALL absorbs).
// Ordering T1-add -> counter-bump is instead enforced by data dependence on
// the RETURNING T1 atomic (RMW complete at coherence point before its old
// value exists; counter increment derived from it). No fence, no inval.

#define NSCALES 67
#define IMG_H 256
#define IMG_W 256
#define NPIX 65536
#define NLINES 2046          // 512 rows (H) + 512 cols (V) + 1022 diagonals (D)
#define LMAX_PAD 320         // 256 positions + 64 zero pad (max tap index 318)

// ws layout (doubles), memset to 0 each launch:
//  [0..4]  b0 {S1, S2, posCnt, sumAbsPrd, roiSum}
//  [5..9]  b1 same
//  [10..11] T1[b]
//  [12]     completion counter (int)
#define T1_OFF 10
#define CNT_OFF 12

__device__ __forceinline__ double wave_red(double v) {
#pragma unroll
  for (int o = 32; o > 0; o >>= 1) v += __shfl_down(v, o, 64);
  return v;
}

__device__ __forceinline__ void decode_line(int id, int& b, int& base, int& stride, int& L) {
  if (id < 512) {                      // horizontal row
    b = id >> 8; int y = id & 255;
    base = y * IMG_W; stride = 1; L = IMG_W;
  } else if (id < 1024) {              // vertical column
    int t = id - 512; b = t >> 8;
    base = t & 255; stride = IMG_W; L = IMG_H;
  } else {                             // diagonal c = x - y in [-255,255]
    int t = id - 1024; b = (t >= 511) ? 1 : 0;
    int d = t - b * 511; int c = d - 255;
    int ac = (c < 0) ? -c : c;
    base = (c < 0) ? (-c) * IMG_W : c;
    stride = IMG_W + 1; L = 256 - ac;
  }
}

// #scales valid for quarter q (centers [64q,64q+63]): s = 1+3k <= min(L-1-64q, 199)
__device__ __forceinline__ int scale_count(int L, int q) {
  int rem = L - 1 - (q << 6);
  int kcnt = (rem >= 1) ? ((rem - 1) / 3 + 1) : 0;
  return (kcnt > NSCALES) ? NSCALES : kcnt;
}

// Stage line into split float4 LDS; returns this tid's ROI value.
__device__ __forceinline__ float stage_line(
    const float* __restrict__ Pred, const float* __restrict__ GT,
    const float* __restrict__ ROI, int b, int base, int stride, int L,
    int tid, float4* bufA, float4* bufB) {
  const float* P = Pred + b * (3 * NPIX);
  const float* G = GT + b * (3 * NPIX);
  const float* R = ROI + b * NPIX;
  float r = 0.f, p0 = 0.f, p1 = 0.f, p2 = 0.f, g0 = 0.f, g1 = 0.f, g2 = 0.f;
  if (tid < L) {
    int a = base + tid * stride;
    r = R[a];
    p0 = P[a]; p1 = P[a + NPIX]; p2 = P[a + 2 * NPIX];
    g0 = G[a]; g1 = G[a + NPIX]; g2 = G[a + 2 * NPIX];
  }
  bufA[tid] = make_float4(r, p0, p1, p2);
  bufB[tid] = make_float4(g0, g1, g2, 0.f);
  if (tid < LMAX_PAD - 256) {
    bufA[256 + tid] = make_float4(0.f, 0.f, 0.f, 0.f);
    bufB[256 + tid] = make_float4(0.f, 0.f, 0.f, 0.f);
  }
  __syncthreads();
  return r;
}

extern "C" __global__ void __launch_bounds__(256, 8) pass1_kernel(
    const float* __restrict__ Pred, const float* __restrict__ GT,
    const float* __restrict__ ROI, double* __restrict__ ws) {
  __shared__ float4 bufA[LMAX_PAD];    // {r, p0, p1, p2}
  __shared__ float4 bufB[LMAX_PAD];    // {g0, g1, g2, 0}
  __shared__ double red[4][5];
  const int id = blockIdx.x;
  const int tid = threadIdx.x;
  const int wid = tid >> 6, lane = tid & 63;

  int b, base, stride, L;
  decode_line(id, b, base, stride, L);
  float stg_r = stage_line(Pred, GT, ROI, b, base, stride, L, tid, bufA, bufB);

  float f1 = 0.f, f2 = 0.f, fp = 0.f;
  int pci = 0;
  int P = 0;                            // task prefix
  for (int q = 0; q < 4; ++q) {
    const int Kq = scale_count(L, q);
    int k = (wid - P) & 3;              // first task of run q owned by this wave
    if (k < Kq) {
      const int c = (q << 6) + lane;
      const float4 cA = bufA[c];
      const float4 cB = bufB[c];
      const float cr = cA.x, cp0 = cA.y, cp1 = cA.z, cp2 = cA.w;
      const float cg0 = cB.x, cg1 = cB.y, cg2 = cB.z;
      const float4* tA = &bufA[c + 1 + 3 * k];
      const float4* tB = &bufB[c + 1 + 3 * k];
#pragma unroll 2
      for (; k < Kq; k += 4) {
        float4 t0 = tA[0];
        float4 t1 = tB[0];
        tA += 12; tB += 12;             // s += 12
        float rr = cr * t0.x;
#define L1BODY(cp, cg, tp, tg)                                   \
        {                                                        \
          float dP = rr * (cp - tp);                             \
          float dG = rr * (cg - tg);                             \
          float qq = dP * __builtin_amdgcn_rcpf(dG + 1e-5f);     \
          float aG = fabsf(dG);                                  \
          f1 += fmaxf(aG * qq, 0.f);                             \
          if (qq > 0.f) f2 += aG;                                \
          if (dG > 0.f) pci++;                                   \
          fp += fabsf(dP);                                       \
        }
        L1BODY(cp0, cg0, t0.y, t1.x)
        L1BODY(cp1, cg1, t0.z, t1.y)
        L1BODY(cp2, cg2, t0.w, t1.z)
#undef L1BODY
      }
    }
    P += Kq;
  }

  double w0 = wave_red((double)f1);
  double w1 = wave_red((double)f2);
  double w2 = wave_red((double)pci);
  double w3 = wave_red((double)fp);
  double w4 = wave_red((double)((id < 512) ? stg_r : 0.f));  // ROI: H rows only
  if (lane == 0) {
    red[wid][0] = w0; red[wid][1] = w1; red[wid][2] = w2;
    red[wid][3] = w3; red[wid][4] = w4;
  }
  __syncthreads();
  if (tid < 5)                          // 5 lanes -> 5 distinct accumulators
    unsafeAtomicAdd(&ws[b * 5 + tid],
                    red[0][tid] + red[1][tid] + red[2][tid] + red[3][tid]);
}

extern "C" __global__ void __launch_bounds__(256, 8) pass2_kernel(
    const float* __restrict__ Pred, const float* __restrict__ GT,
    const float* __restrict__ ROI, double* __restrict__ ws,
    float* __restrict__ out) {
  __shared__ float4 bufA[LMAX_PAD];
  __shared__ float4 bufB[LMAX_PAD];
  __shared__ double red[4];
  __shared__ float s_invC;
  __shared__ int s_isLast;
  const int id = blockIdx.x;
  const int tid = threadIdx.x;
  const int wid = tid >> 6, lane = tid & 63;

  int b, base, stride, L;
  decode_line(id, b, base, stride, L);
  if (tid == 0) {                       // 2 plain f64 loads across the kernel
    double S1 = ws[b * 5 + 0];          // boundary (R5/R7-proven coherent)
    double S2 = ws[b * 5 + 1];
    float cc = (float)(S1 / (S2 + 1e-4));
    s_invC = (cc > 1e-4f) ? (float)(1.0 / (double)cc) : 1.0f;
  }
  stage_line(Pred, GT, ROI, b, base, stride, L, tid, bufA, bufB);

  const float invC = s_invC;
  float f = 0.f;
  int P = 0;
  for (int q = 0; q < 4; ++q) {
    const int Kq = scale_count(L, q);
    int k = (wid - P) & 3;
    if (k < Kq) {
      const int c = (q << 6) + lane;
      const float4 cA = bufA[c];
      const float4 cB = bufB[c];
      const float cr = cA.x, cp0 = cA.y, cp1 = cA.z, cp2 = cA.w;
      const float cg0 = cB.x, cg1 = cB.y, cg2 = cB.z;
      const float4* tA = &bufA[c + 1 + 3 * k];
      const float4* tB = &bufB[c + 1 + 3 * k];
#pragma unroll 2
      for (; k < Kq; k += 4) {
        float4 t0 = tA[0];
        float4 t1 = tB[0];
        tA += 12; tB += 12;
        float rr = cr * t0.x;
        // |difGT - difPrd/c| = rr * |(g-gt) - (p-pt)*invC|   (rr in {0,1})
        f += rr * fabsf((cg0 - t1.x) - (cp0 - t0.y) * invC);
        f += rr * fabsf((cg1 - t1.y) - (cp1 - t0.z) * invC);
        f += rr * fabsf((cg2 - t1.z) - (cp2 - t0.w) * invC);
      }
    }
    P += Kq;
  }
  double t = wave_red((double)f);
  if (lane == 0) red[wid] = t;
  __syncthreads();
  if (tid == 0) {
    // Returning atomic: RMW complete at the coherence point before oldv
    // exists. Deriving the counter increment from oldv (always 1; partial
    // sums are >= 0, compiler can't prove it) orders add -> bump w/o fence.
    double oldv = unsafeAtomicAdd(&ws[T1_OFF + b],
                                  red[0] + red[1] + red[2] + red[3]);
    int inc = (oldv > -1.0e300) ? 1 : 2;
    int old = atomicAdd((int*)&ws[CNT_OFF], inc);
    s_isLast = (old == NLINES - 1);
  }
  __syncthreads();

  if (s_isLast && tid == 0) {           // last-block epilogue (R8-proven)
    double T1v[2];
    T1v[0] = unsafeAtomicAdd(&ws[T1_OFF + 0], 0.0);   // atomic readback at
    T1v[1] = unsafeAtomicAdd(&ws[T1_OFF + 1], 0.0);   // the coherence point
    double loss = 0.0;
    for (int bb = 0; bb < 2; ++bb) {
      double S1 = ws[bb * 5 + 0], S2 = ws[bb * 5 + 1];  // pass1-written: plain
      double PC = ws[bb * 5 + 2], SP = ws[bb * 5 + 3];  // loads are coherent
      double RS = ws[bb * 5 + 4];                       // across the boundary
      float cc = (float)(S1 / (S2 + 1e-4));
      out[1 + bb] = cc;                 // NormConst
      double term1 = (cc > 1e-4f) ? T1v[bb] / (603.0 * 65536.0) : 0.0;
      float meanPrd = (float)(SP / PC);
      bool big = RS > 200.0;
      float t2 = (big && meanPrd > 30.f && cc > 10.f) ? (meanPrd - 30.f) : 0.f;
      float fact = 0.1f / (cc + 0.001f);
      float t3 = (big && meanPrd < 2.f && cc < 0.1f) ? (0.2f - meanPrd) * fact : 0.f;
      loss += term1 + (double)(t2 + t3);
    }
    out[0] = (float)loss;
  }
}

extern "C" void kernel_launch(void* const* d_in, const int* in_sizes, int n_in,
                              void* d_out, int out_size, void* d_ws, size_t ws_size,
                              hipStream_t stream) {
  (void)in_sizes; (void)n_in; (void)out_size; (void)ws_size;
  const float* Pred = (const float*)d_in[0];
  const float* GT = (const float*)d_in[1];
  const float* ROI = (const float*)d_in[2];
  float* out = (float*)d_out;
  double* ws = (double*)d_ws;

  hipMemsetAsync(d_ws, 0, 16 * sizeof(double), stream);   // sums+T1+counter
  hipLaunchKernelGGL(pass1_kernel, dim3(NLINES), dim3(256), 0, stream,
                     Pred, GT, ROI, ws);
  hipLaunchKernelGGL(pass2_kernel, dim3(NLINES), dim3(256), 0, stream,
                     Pred, GT, ROI, ws, out);
}